// Round 8
// baseline (409.939 us; speedup 1.0000x reference)
//
#include <hip/hip_runtime.h>
#include <hip/hip_bf16.h>
#include <math.h>

typedef __attribute__((ext_vector_type(8))) short short8;
typedef __attribute__((ext_vector_type(4))) float f32x4;

__device__ inline unsigned short f2bf(float x) {
    union { float f; unsigned u; } v; v.f = x;
    unsigned r = v.u + 0x7fff + ((v.u >> 16) & 1);
    return (unsigned short)(r >> 16);
}
__device__ inline float bf2f(unsigned short h) {
    union { unsigned u; float f; } v; v.u = ((unsigned)h) << 16;
    return v.f;
}

// ---------------- W prep: transpose [768][128] f32 -> [128][768] bf16 hi/lo ----------------
__global__ __launch_bounds__(256) void prep_w_kernel(
    const float* __restrict__ Wm, unsigned short* __restrict__ wht,
    unsigned short* __restrict__ wlt)
{
    const int tid = threadIdx.x;
    const int n = tid & 127;
    const int kg = tid >> 7;                 // 0..1
    const int k0 = blockIdx.x * 32 + kg * 16;
    short8 hi0, hi1, lo0, lo1;
#pragma unroll
    for (int j = 0; j < 16; ++j) {
        const float wv = Wm[(size_t)(k0 + j) * 128 + n];
        const unsigned short h = f2bf(wv);
        const unsigned short l = f2bf(wv - bf2f(h));
        if (j < 8) { hi0[j] = (short)h; lo0[j] = (short)l; }
        else       { hi1[j - 8] = (short)h; lo1[j - 8] = (short)l; }
    }
    short* whp = reinterpret_cast<short*>(wht) + (size_t)n * 768 + k0;
    short* wlp = reinterpret_cast<short*>(wlt) + (size_t)n * 768 + k0;
    *reinterpret_cast<short8*>(whp) = hi0;
    *reinterpret_cast<short8*>(whp + 8) = hi1;
    *reinterpret_cast<short8*>(wlp) = lo0;
    *reinterpret_cast<short8*>(wlp + 8) = lo1;
}

// ---------------- projection via split-bf16 MFMA + L2 norm + mask-zeroing ----------------
// block = 4 waves x 16 rows = 64 rows -> 512 blocks = 2 blocks/CU = 8 waves/CU.
// Wave: 1 m-frag x 8 n-frags, K=768 (24 kc). Each row converted exactly once;
// W kc-slice (16 KB) reused across waves via L1.
// C = (ah+al)@(wh+wl) ~= ah@wh + al@wh + ah@wl  (error ~2^-17, f32-equivalent)
__global__ __launch_bounds__(256, 2) void proj_mfma_kernel(
    const float* __restrict__ src, const unsigned short* __restrict__ wht,
    const unsigned short* __restrict__ wlt, const float* __restrict__ bias,
    const int* __restrict__ mask, unsigned short* __restrict__ dst)
{
    const int tid = threadIdx.x;
    const int lane = tid & 63, w = tid >> 6;
    const int lq = lane >> 4, lr = lane & 15;
    const int rbase = blockIdx.x * 64 + w * 16;

    f32x4 acc[8];
#pragma unroll
    for (int n = 0; n < 8; ++n) acc[n] = (f32x4)(0.f);

    float bb[8];
#pragma unroll
    for (int n = 0; n < 8; ++n) bb[n] = bias[n * 16 + lr];

    const float* ap = src + (size_t)(rbase + lr) * 768 + lq * 8;
    const short* whp = reinterpret_cast<const short*>(wht) + (size_t)lr * 768 + lq * 8;
    const short* wlp = reinterpret_cast<const short*>(wlt) + (size_t)lr * 768 + lq * 8;

#pragma unroll 2
    for (int kc = 0; kc < 24; ++kc) {
        f32x4 a0 = *reinterpret_cast<const f32x4*>(ap + kc * 32);
        f32x4 a1 = *reinterpret_cast<const f32x4*>(ap + kc * 32 + 4);
        short8 ah, al;
#pragma unroll
        for (int j = 0; j < 8; ++j) {
            const float av = (j < 4) ? a0[j] : a1[j - 4];
            const unsigned short h = f2bf(av);
            const unsigned short l = f2bf(av - bf2f(h));
            ah[j] = (short)h; al[j] = (short)l;
        }
        short8 wh[8];
#pragma unroll
        for (int n = 0; n < 8; ++n)
            wh[n] = *reinterpret_cast<const short8*>(whp + (size_t)n * 16 * 768 + kc * 32);
#pragma unroll
        for (int n = 0; n < 8; ++n)
            acc[n] = __builtin_amdgcn_mfma_f32_16x16x32_bf16(ah, wh[n], acc[n], 0, 0, 0);
#pragma unroll
        for (int n = 0; n < 8; ++n)
            acc[n] = __builtin_amdgcn_mfma_f32_16x16x32_bf16(al, wh[n], acc[n], 0, 0, 0);
        short8 wl[8];
#pragma unroll
        for (int n = 0; n < 8; ++n)
            wl[n] = *reinterpret_cast<const short8*>(wlp + (size_t)n * 16 * 768 + kc * 32);
#pragma unroll
        for (int n = 0; n < 8; ++n)
            acc[n] = __builtin_amdgcn_mfma_f32_16x16x32_bf16(ah, wl[n], acc[n], 0, 0, 0);
    }

    // epilogue: bias, row L2 norm (rows = rbase + lq*4 + i2), mask-zero, bf16 store
#pragma unroll
    for (int n = 0; n < 8; ++n)
#pragma unroll
        for (int i2 = 0; i2 < 4; ++i2) acc[n][i2] += bb[n];
    float ss[4];
#pragma unroll
    for (int i2 = 0; i2 < 4; ++i2) {
        float s = 0.f;
#pragma unroll
        for (int n = 0; n < 8; ++n) s += acc[n][i2] * acc[n][i2];
        s += __shfl_xor(s, 1); s += __shfl_xor(s, 2);
        s += __shfl_xor(s, 4); s += __shfl_xor(s, 8);
        ss[i2] = s;
    }
#pragma unroll
    for (int i2 = 0; i2 < 4; ++i2) {
        const int row = rbase + lq * 4 + i2;
        float inv = 1.0f / fmaxf(sqrtf(ss[i2]), 1e-12f);
        if (mask[row] == 0) inv = 0.f;   // fold mask into embedding (zeroed rows)
#pragma unroll
        for (int n = 0; n < 8; ++n)
            dst[(size_t)row * 128 + n * 16 + lr] = f2bf(acc[n][i2] * inv);
    }
}

// ---------------- maxsim: barrier-free, wave = 4 labels x 256 text rows ----------------
// Masks pre-folded: masked text rows -> sim 0 (never wins max, true colmax > 0 w.p. 1);
// masked label cols -> colmax exactly 0 -> drop out of the sum.
__global__ __launch_bounds__(256, 2) void maxsim_kernel(
    const unsigned short* __restrict__ temb,  // [32768][128] bf16
    const unsigned short* __restrict__ lemb,  // [4096][128] bf16
    float* __restrict__ sums)                 // [128][128] raw col-max sums
{
    const int t = blockIdx.x;                 // grid (128,8): wgid%8 = t%8 -> XCD locality
    const int bg = blockIdx.y;
    const int tid = threadIdx.x;
    const int lane = tid & 63, w = tid >> 6;
    const int lq = lane >> 4, lr = lane & 15;
    const short* tp = reinterpret_cast<const short*>(temb);
    const short* lp = reinterpret_cast<const short*>(lemb);
    const int l0 = bg * 16 + w * 4;           // this wave's first label

    short8 bfr[8][4];
#pragma unroll
    for (int n = 0; n < 8; ++n)
#pragma unroll
        for (int kc = 0; kc < 4; ++kc)
            bfr[n][kc] = *reinterpret_cast<const short8*>(
                lp + (size_t)(l0 * 32 + n * 16 + lr) * 128 + kc * 32 + lq * 8);

    f32x4 cmx[8];
#pragma unroll
    for (int n = 0; n < 8; ++n) cmx[n] = (f32x4)(-1e30f);

    const short* ap0 = tp + (size_t)(t * 256 + lr) * 128 + lq * 8;

    for (int m = 0; m < 16; ++m) {
        short8 afr[4];
#pragma unroll
        for (int kc = 0; kc < 4; ++kc)
            afr[kc] = *reinterpret_cast<const short8*>(ap0 + (size_t)m * 16 * 128 + kc * 32);
        f32x4 acc[8];
#pragma unroll
        for (int n = 0; n < 8; ++n) acc[n] = (f32x4)(0.f);
#pragma unroll
        for (int kc = 0; kc < 4; ++kc)
#pragma unroll
            for (int n = 0; n < 8; ++n)
                acc[n] = __builtin_amdgcn_mfma_f32_16x16x32_bf16(afr[kc], bfr[n][kc], acc[n], 0, 0, 0);
#pragma unroll
        for (int n = 0; n < 8; ++n) {
            cmx[n][0] = fmaxf(cmx[n][0], acc[n][0]);
            cmx[n][1] = fmaxf(cmx[n][1], acc[n][1]);
            cmx[n][2] = fmaxf(cmx[n][2], acc[n][2]);
            cmx[n][3] = fmaxf(cmx[n][3], acc[n][3]);
        }
    }

    float s[8];
#pragma unroll
    for (int n = 0; n < 8; ++n) {
        float v = fmaxf(fmaxf(cmx[n][0], cmx[n][1]), fmaxf(cmx[n][2], cmx[n][3]));
        v = fmaxf(v, __shfl_xor(v, 16));      // max over lq (rows)
        v = fmaxf(v, __shfl_xor(v, 32));
        v += __shfl_xor(v, 1);                // sum over lr (16 cols of frag)
        v += __shfl_xor(v, 2);
        v += __shfl_xor(v, 4);
        v += __shfl_xor(v, 8);
        s[n] = v;
    }
    if (lane == 0) {
#pragma unroll
        for (int li = 0; li < 4; ++li)
            sums[t * 128 + l0 + li] = s[2 * li] + s[2 * li + 1];
    }
}

// ---------------- finalize: label counts + scale/mean + sigmoid + BCE ----------------
__global__ __launch_bounds__(256) void finalize_kernel(
    const float* __restrict__ sums, const int* __restrict__ lmask,
    const float* __restrict__ targets, const float* __restrict__ scale_p,
    float* __restrict__ out)
{
    __shared__ float cl[128];
    const int tid = threadIdx.x;
    if (tid < 128) {
        int c = 0;
#pragma unroll
        for (int r = 0; r < 32; ++r) c += lmask[tid * 32 + r];
        cl[tid] = fmaxf((float)c, 1.0f);
    }
    __syncthreads();
    const float scale = *scale_p;
    float sum = 0.f;
    for (int i = tid; i < 16384; i += 256) {
        const float x = scale * sums[i] / cl[i & 127];
        const float tg = targets[i];
        out[1 + i] = 1.0f / (1.0f + expf(-x));
        sum += fmaxf(x, 0.f) - x * tg + log1pf(expf(-fabsf(x)));
    }
    __shared__ float part[4];
#pragma unroll
    for (int msk = 32; msk >= 1; msk >>= 1) sum += __shfl_xor(sum, msk);
    if ((tid & 63) == 0) part[tid >> 6] = sum;
    __syncthreads();
    if (tid == 0)
        out[0] = (part[0] + part[1] + part[2] + part[3]) * (1.0f / 16384.0f);
}

extern "C" void kernel_launch(void* const* d_in, const int* in_sizes, int n_in,
                              void* d_out, int out_size, void* d_ws, size_t ws_size,
                              hipStream_t stream) {
    const float* text_hidden  = (const float*)d_in[0];
    const float* label_hidden = (const float*)d_in[1];
    const int*   text_mask    = (const int*)d_in[2];
    const int*   label_mask   = (const int*)d_in[3];
    const float* targets      = (const float*)d_in[4];
    const float* W_proj       = (const float*)d_in[5];
    const float* b_proj       = (const float*)d_in[6];
    const float* score_scale  = (const float*)d_in[7];
    float* out = (float*)d_out;

    char* ws = (char*)d_ws;
    unsigned short* temb = (unsigned short*)(ws);                    // 8 MB
    unsigned short* lemb = (unsigned short*)(ws + 8388608);          // 1 MB
    float*          sums = (float*)(ws + 9437184);                   // 64 KB
    unsigned short* wht  = (unsigned short*)(ws + 9502720);          // 192 KB
    unsigned short* wlt  = (unsigned short*)(ws + 9699328);          // 192 KB

    prep_w_kernel<<<24, 256, 0, stream>>>(W_proj, wht, wlt);
    proj_mfma_kernel<<<512, 256, 0, stream>>>(text_hidden, wht, wlt, b_proj,
                                              text_mask, temb);
    proj_mfma_kernel<<<64, 256, 0, stream>>>(label_hidden, wht, wlt, b_proj,
                                             label_mask, lemb);
    maxsim_kernel<<<dim3(128, 8), 256, 0, stream>>>(temb, lemb, sums);
    finalize_kernel<<<1, 256, 0, stream>>>(sums, label_mask, targets, score_scale, out);
}

// Round 9
// 297.881 us; speedup vs baseline: 1.3762x; 1.3762x over previous
//
#include <hip/hip_runtime.h>
#include <hip/hip_bf16.h>
#include <math.h>

typedef __attribute__((ext_vector_type(8))) short short8;
typedef __attribute__((ext_vector_type(4))) float f32x4;

__device__ inline unsigned short f2bf(float x) {
    union { float f; unsigned u; } v; v.f = x;
    unsigned r = v.u + 0x7fff + ((v.u >> 16) & 1);
    return (unsigned short)(r >> 16);
}
__device__ inline float bf2f(unsigned short h) {
    union { unsigned u; float f; } v; v.u = ((unsigned)h) << 16;
    return v.f;
}

// ---------------- W prep: [768][128] f32 -> fragment-ordered bf16 hi/lo ----------------
// wfrag = 12 chunks x 32KB. Chunk c: [hi 16KB][lo 16KB]; slot s in [0,1024):
//   kcl=s>>9, rem=s&511, fq=rem>>6, l=rem&63, lq=l>>4, lr=l&15
//   n = fq*16+lr, k = c*64 + kcl*32 + lq*8  (8 k-elems per slot)
// Proj reads frag (c,kcl,fq) at shorts [kcl*4096 + fq*512 + lane*8] -> lane-linear b128.
__global__ __launch_bounds__(256) void prep_w_kernel(
    const float* __restrict__ Wm, unsigned short* __restrict__ wfrag)
{
    const int g = blockIdx.x * 256 + threadIdx.x;   // 12288 slots
    const int c = g >> 10, s = g & 1023;
    const int rem = s & 511;
    const int l = rem & 63;
    const int n = ((rem >> 6) << 4) + (l & 15);
    const int k = c * 64 + ((s >> 9) << 5) + ((l >> 4) << 3);
    short8 hi, lo;
#pragma unroll
    for (int j = 0; j < 8; ++j) {
        const float wv = Wm[(size_t)(k + j) * 128 + n];
        const unsigned short h = f2bf(wv);
        hi[j] = (short)h;
        lo[j] = (short)f2bf(wv - bf2f(h));
    }
    *reinterpret_cast<short8*>(wfrag + (size_t)c * 16384 + s * 8) = hi;
    *reinterpret_cast<short8*>(wfrag + (size_t)c * 16384 + 8192 + s * 8) = lo;
}

// ---------------- projection: LDS-staged W, double-buffered, merged text+label ----------
// block = 4 waves x 32 rows = 128 rows; 288 blocks. Chunk = 64 K-elems (2 kc),
// 12 chunks. LDS 2 x 32KB. Per chunk/wave: 8 A-loads, 8 W-stage loads (coalesced),
// 32 ds_read_b128 (lane-linear, conflict-free), 96 MFMA.
__global__ __launch_bounds__(256, 2) void proj_mfma_kernel(
    const float* __restrict__ th, const float* __restrict__ lh,
    const unsigned short* __restrict__ wfrag, const float* __restrict__ bias,
    const int* __restrict__ tmask, const int* __restrict__ lmask,
    unsigned short* __restrict__ emb)
{
    __shared__ short lds[2][16384];   // 2 x 32 KB
    const int tid = threadIdx.x;
    const int lane = tid & 63, w = tid >> 6;
    const int lq = lane >> 4, lr = lane & 15;
    const int rowg = blockIdx.x * 128;

    const float* sp; const int* mp;
    if (rowg < 32768) { sp = th + (size_t)rowg * 768; mp = tmask + rowg; }
    else { sp = lh + (size_t)(rowg - 32768) * 768; mp = lmask + (rowg - 32768); }

    const float* ap0 = sp + (size_t)(w * 32 + lr) * 768 + lq * 8;  // m=0 rows
    const float* ap1 = ap0 + (size_t)16 * 768;                     // m=1 rows
    const short* wsrc = reinterpret_cast<const short*>(wfrag);

    f32x4 acc[2][8];
#pragma unroll
    for (int m = 0; m < 2; ++m)
#pragma unroll
        for (int n = 0; n < 8; ++n) acc[m][n] = (f32x4)(0.f);

    float bb[8];
#pragma unroll
    for (int n = 0; n < 8; ++n) bb[n] = bias[n * 16 + lr];

    short8 wst[8];
    f32x4 aA[8];   // A chunk regs: idx = m*4 + kcl*2 + h

    // prologue: stage chunk0, load A(0), issue W(1)
#pragma unroll
    for (int j = 0; j < 8; ++j)
        wst[j] = *reinterpret_cast<const short8*>(wsrc + (j * 256 + tid) * 8);
#pragma unroll
    for (int j = 0; j < 8; ++j)
        *reinterpret_cast<short8*>(&lds[0][(j * 256 + tid) * 8]) = wst[j];
#pragma unroll
    for (int m = 0; m < 2; ++m)
#pragma unroll
        for (int kcl = 0; kcl < 2; ++kcl)
#pragma unroll
            for (int h = 0; h < 2; ++h)
                aA[m * 4 + kcl * 2 + h] = *reinterpret_cast<const f32x4*>(
                    (m ? ap1 : ap0) + kcl * 32 + h * 4);
#pragma unroll
    for (int j = 0; j < 8; ++j)
        wst[j] = *reinterpret_cast<const short8*>(wsrc + 16384 + (j * 256 + tid) * 8);
    __syncthreads();

    for (int c = 0; c < 12; ++c) {
        const int cb = c & 1;
        // convert A(c) -> bf16 hi/lo fragments (frees aA)
        short8 ah[2][2], al[2][2];
#pragma unroll
        for (int m = 0; m < 2; ++m)
#pragma unroll
            for (int kcl = 0; kcl < 2; ++kcl) {
                const f32x4 x0 = aA[m * 4 + kcl * 2], x1 = aA[m * 4 + kcl * 2 + 1];
#pragma unroll
                for (int j = 0; j < 8; ++j) {
                    const float av = (j < 4) ? x0[j] : x1[j - 4];
                    const unsigned short h = f2bf(av);
                    ah[m][kcl][j] = (short)h;
                    al[m][kcl][j] = (short)f2bf(av - bf2f(h));
                }
            }
        // issue A(c+1) into freed regs
        if (c < 11) {
#pragma unroll
            for (int m = 0; m < 2; ++m)
#pragma unroll
                for (int kcl = 0; kcl < 2; ++kcl)
#pragma unroll
                    for (int h = 0; h < 2; ++h)
                        aA[m * 4 + kcl * 2 + h] = *reinterpret_cast<const f32x4*>(
                            (m ? ap1 : ap0) + (c + 1) * 64 + kcl * 32 + h * 4);
        }
        // compute chunk c from lds[cb]
#pragma unroll
        for (int kcl = 0; kcl < 2; ++kcl) {
            short8 wf[8];
#pragma unroll
            for (int n = 0; n < 8; ++n)
                wf[n] = *reinterpret_cast<const short8*>(
                    &lds[cb][kcl * 4096 + n * 512 + lane * 8]);
#pragma unroll
            for (int m = 0; m < 2; ++m)
#pragma unroll
                for (int n = 0; n < 8; ++n)
                    acc[m][n] = __builtin_amdgcn_mfma_f32_16x16x32_bf16(
                        ah[m][kcl], wf[n], acc[m][n], 0, 0, 0);
#pragma unroll
            for (int m = 0; m < 2; ++m)
#pragma unroll
                for (int n = 0; n < 8; ++n)
                    acc[m][n] = __builtin_amdgcn_mfma_f32_16x16x32_bf16(
                        al[m][kcl], wf[n], acc[m][n], 0, 0, 0);
#pragma unroll
            for (int n = 0; n < 8; ++n)
                wf[n] = *reinterpret_cast<const short8*>(
                    &lds[cb][8192 + kcl * 4096 + n * 512 + lane * 8]);
#pragma unroll
            for (int m = 0; m < 2; ++m)
#pragma unroll
                for (int n = 0; n < 8; ++n)
                    acc[m][n] = __builtin_amdgcn_mfma_f32_16x16x32_bf16(
                        ah[m][kcl], wf[n], acc[m][n], 0, 0, 0);
        }
        // write staged W(c+1) into the other buffer; issue W(c+2)
        if (c < 11) {
#pragma unroll
            for (int j = 0; j < 8; ++j)
                *reinterpret_cast<short8*>(&lds[cb ^ 1][(j * 256 + tid) * 8]) = wst[j];
        }
        if (c < 10) {
#pragma unroll
            for (int j = 0; j < 8; ++j)
                wst[j] = *reinterpret_cast<const short8*>(
                    wsrc + (size_t)(c + 2) * 16384 + (j * 256 + tid) * 8);
        }
        __syncthreads();
    }

    // epilogue: bias, row L2 norm, mask-zero, bf16 store
#pragma unroll
    for (int m = 0; m < 2; ++m) {
#pragma unroll
        for (int n = 0; n < 8; ++n)
#pragma unroll
            for (int i2 = 0; i2 < 4; ++i2) acc[m][n][i2] += bb[n];
        float ss[4];
#pragma unroll
        for (int i2 = 0; i2 < 4; ++i2) {
            float s = 0.f;
#pragma unroll
            for (int n = 0; n < 8; ++n) s += acc[m][n][i2] * acc[m][n][i2];
            s += __shfl_xor(s, 1); s += __shfl_xor(s, 2);
            s += __shfl_xor(s, 4); s += __shfl_xor(s, 8);
            ss[i2] = s;
        }
#pragma unroll
        for (int i2 = 0; i2 < 4; ++i2) {
            const int rowl = w * 32 + m * 16 + lq * 4 + i2;
            float inv = 1.0f / fmaxf(sqrtf(ss[i2]), 1e-12f);
            if (mp[rowl] == 0) inv = 0.f;   // fold mask into embedding
#pragma unroll
            for (int n = 0; n < 8; ++n)
                emb[(size_t)(rowg + rowl) * 128 + n * 16 + lr] = f2bf(acc[m][n][i2] * inv);
        }
    }
}

// ---------------- maxsim: barrier-free, wave = 4 labels x 256 text rows ----------------
__global__ __launch_bounds__(256, 2) void maxsim_kernel(
    const unsigned short* __restrict__ temb,  // [32768][128] bf16
    const unsigned short* __restrict__ lemb,  // [4096][128] bf16
    float* __restrict__ sums)                 // [128][128] raw col-max sums
{
    const int t = blockIdx.x;
    const int bg = blockIdx.y;
    const int tid = threadIdx.x;
    const int lane = tid & 63, w = tid >> 6;
    const int lq = lane >> 4, lr = lane & 15;
    const short* tp = reinterpret_cast<const short*>(temb);
    const short* lp = reinterpret_cast<const short*>(lemb);
    const int l0 = bg * 16 + w * 4;

    short8 bfr[8][4];
#pragma unroll
    for (int n = 0; n < 8; ++n)
#pragma unroll
        for (int kc = 0; kc < 4; ++kc)
            bfr[n][kc] = *reinterpret_cast<const short8*>(
                lp + (size_t)(l0 * 32 + n * 16 + lr) * 128 + kc * 32 + lq * 8);

    f32x4 cmx[8];
#pragma unroll
    for (int n = 0; n < 8; ++n) cmx[n] = (f32x4)(-1e30f);

    const short* ap0 = tp + (size_t)(t * 256 + lr) * 128 + lq * 8;

    for (int m = 0; m < 16; ++m) {
        short8 afr[4];
#pragma unroll
        for (int kc = 0; kc < 4; ++kc)
            afr[kc] = *reinterpret_cast<const short8*>(ap0 + (size_t)m * 16 * 128 + kc * 32);
        f32x4 acc[8];
#pragma unroll
        for (int n = 0; n < 8; ++n) acc[n] = (f32x4)(0.f);
#pragma unroll
        for (int kc = 0; kc < 4; ++kc)
#pragma unroll
            for (int n = 0; n < 8; ++n)
                acc[n] = __builtin_amdgcn_mfma_f32_16x16x32_bf16(afr[kc], bfr[n][kc], acc[n], 0, 0, 0);
#pragma unroll
        for (int n = 0; n < 8; ++n) {
            cmx[n][0] = fmaxf(cmx[n][0], acc[n][0]);
            cmx[n][1] = fmaxf(cmx[n][1], acc[n][1]);
            cmx[n][2] = fmaxf(cmx[n][2], acc[n][2]);
            cmx[n][3] = fmaxf(cmx[n][3], acc[n][3]);
        }
    }

    float s[8];
#pragma unroll
    for (int n = 0; n < 8; ++n) {
        float v = fmaxf(fmaxf(cmx[n][0], cmx[n][1]), fmaxf(cmx[n][2], cmx[n][3]));
        v = fmaxf(v, __shfl_xor(v, 16));
        v = fmaxf(v, __shfl_xor(v, 32));
        v += __shfl_xor(v, 1);
        v += __shfl_xor(v, 2);
        v += __shfl_xor(v, 4);
        v += __shfl_xor(v, 8);
        s[n] = v;
    }
    if (lane == 0) {
#pragma unroll
        for (int li = 0; li < 4; ++li)
            sums[t * 128 + l0 + li] = s[2 * li] + s[2 * li + 1];
    }
}

// ---------------- finalize: label counts + scale/mean + sigmoid + BCE ----------------
__global__ __launch_bounds__(256) void finalize_kernel(
    const float* __restrict__ sums, const int* __restrict__ lmask,
    const float* __restrict__ targets, const float* __restrict__ scale_p,
    float* __restrict__ out)
{
    __shared__ float cl[128];
    const int tid = threadIdx.x;
    if (tid < 128) {
        int c = 0;
#pragma unroll
        for (int r = 0; r < 32; ++r) c += lmask[tid * 32 + r];
        cl[tid] = fmaxf((float)c, 1.0f);
    }
    __syncthreads();
    const float scale = *scale_p;
    float sum = 0.f;
    for (int i = tid; i < 16384; i += 256) {
        const float x = scale * sums[i] / cl[i & 127];
        const float tg = targets[i];
        out[1 + i] = 1.0f / (1.0f + expf(-x));
        sum += fmaxf(x, 0.f) - x * tg + log1pf(expf(-fabsf(x)));
    }
    __shared__ float part[4];
#pragma unroll
    for (int msk = 32; msk >= 1; msk >>= 1) sum += __shfl_xor(sum, msk);
    if ((tid & 63) == 0) part[tid >> 6] = sum;
    __syncthreads();
    if (tid == 0)
        out[0] = (part[0] + part[1] + part[2] + part[3]) * (1.0f / 16384.0f);
}

extern "C" void kernel_launch(void* const* d_in, const int* in_sizes, int n_in,
                              void* d_out, int out_size, void* d_ws, size_t ws_size,
                              hipStream_t stream) {
    const float* text_hidden  = (const float*)d_in[0];
    const float* label_hidden = (const float*)d_in[1];
    const int*   text_mask    = (const int*)d_in[2];
    const int*   label_mask   = (const int*)d_in[3];
    const float* targets      = (const float*)d_in[4];
    const float* W_proj       = (const float*)d_in[5];
    const float* b_proj       = (const float*)d_in[6];
    const float* score_scale  = (const float*)d_in[7];
    float* out = (float*)d_out;

    char* ws = (char*)d_ws;
    unsigned short* emb   = (unsigned short*)(ws);            // 36864*128*2 = 9437184 B
    float*          sums  = (float*)(ws + 9437184);           // 64 KB
    unsigned short* wfrag = (unsigned short*)(ws + 9502720);  // 384 KB fragment-ordered W

    prep_w_kernel<<<48, 256, 0, stream>>>(W_proj, wfrag);
    proj_mfma_kernel<<<288, 256, 0, stream>>>(text_hidden, label_hidden, wfrag,
                                              b_proj, text_mask, label_mask, emb);
    maxsim_kernel<<<dim3(128, 8), 256, 0, stream>>>(emb, emb + (size_t)32768 * 128, sums);
    finalize_kernel<<<1, 256, 0, stream>>>(sums, label_mask, targets, score_scale, out);
}

// Round 11
// 250.406 us; speedup vs baseline: 1.6371x; 1.1896x over previous
//
#include <hip/hip_runtime.h>
#include <hip/hip_bf16.h>
#include <math.h>

typedef __attribute__((ext_vector_type(8))) short short8;
typedef __attribute__((ext_vector_type(4))) float f32x4;

__device__ inline unsigned short f2bf(float x) {
    union { float f; unsigned u; } v; v.f = x;
    unsigned r = v.u + 0x7fff + ((v.u >> 16) & 1);
    return (unsigned short)(r >> 16);
}
__device__ inline float bf2f(unsigned short h) {
    union { unsigned u; float f; } v; v.u = ((unsigned)h) << 16;
    return v.f;
}

// ---------------- W prep: [768][128] f32 -> fragment-ordered bf16 hi/lo ----------------
// wfrag = 12 chunks x 32KB. Chunk c: [hi 16KB][lo 16KB]; slot s in [0,1024):
//   kcl=s>>9, rem=s&511, fq=rem>>6, l=rem&63, lq=l>>4, lr=l&15
//   n = fq*16+lr, k = c*64 + kcl*32 + lq*8  (8 k-elems per slot)
__global__ __launch_bounds__(256) void prep_w_kernel(
    const float* __restrict__ Wm, unsigned short* __restrict__ wfrag)
{
    const int g = blockIdx.x * 256 + threadIdx.x;   // 12288 slots
    const int c = g >> 10, s = g & 1023;
    const int rem = s & 511;
    const int l = rem & 63;
    const int n = ((rem >> 6) << 4) + (l & 15);
    const int k = c * 64 + ((s >> 9) << 5) + ((l >> 4) << 3);
    short8 hi, lo;
#pragma unroll
    for (int j = 0; j < 8; ++j) {
        const float wv = Wm[(size_t)(k + j) * 128 + n];
        const unsigned short h = f2bf(wv);
        hi[j] = (short)h;
        lo[j] = (short)f2bf(wv - bf2f(h));
    }
    *reinterpret_cast<short8*>(wfrag + (size_t)c * 16384 + s * 8) = hi;
    *reinterpret_cast<short8*>(wfrag + (size_t)c * 16384 + 8192 + s * 8) = lo;
}

// ---------------- projection: LDS-staged W, double-buffered ----------
// block = 4 waves x 16 rows = 64 rows; 576 blocks = 2.25 blocks/CU (LDS 64KB -> 2
// resident = 2 waves/SIMD). W staged once per block; A prefetched 1 chunk ahead.
__global__ __launch_bounds__(256, 2) void proj_mfma_kernel(
    const float* __restrict__ th, const float* __restrict__ lh,
    const unsigned short* __restrict__ wfrag, const float* __restrict__ bias,
    const int* __restrict__ tmask, const int* __restrict__ lmask,
    unsigned short* __restrict__ emb)
{
    __shared__ short lds[2][16384];   // 2 x 32 KB
    const int tid = threadIdx.x;
    const int lane = tid & 63, w = tid >> 6;
    const int lq = lane >> 4, lr = lane & 15;
    const int rowg = blockIdx.x * 64;

    const float* sp; const int* mp;
    if (rowg < 32768) { sp = th + (size_t)rowg * 768; mp = tmask + rowg; }
    else { sp = lh + (size_t)(rowg - 32768) * 768; mp = lmask + (rowg - 32768); }

    const float* ap = sp + (size_t)(w * 16 + lr) * 768 + lq * 8;
    const short* wsrc = reinterpret_cast<const short*>(wfrag);

    f32x4 acc[8];
#pragma unroll
    for (int n = 0; n < 8; ++n) acc[n] = (f32x4)(0.f);

    float bb[8];
#pragma unroll
    for (int n = 0; n < 8; ++n) bb[n] = bias[n * 16 + lr];

    short8 wst[8];
    f32x4 aA[4];   // A chunk regs: idx = kcl*2 + h

    // prologue: stage chunk0, load A(0), issue W(1)
#pragma unroll
    for (int j = 0; j < 8; ++j)
        wst[j] = *reinterpret_cast<const short8*>(wsrc + (j * 256 + tid) * 8);
#pragma unroll
    for (int j = 0; j < 8; ++j)
        *reinterpret_cast<short8*>(&lds[0][(j * 256 + tid) * 8]) = wst[j];
#pragma unroll
    for (int kcl = 0; kcl < 2; ++kcl)
#pragma unroll
        for (int h = 0; h < 2; ++h)
            aA[kcl * 2 + h] = *reinterpret_cast<const f32x4*>(ap + kcl * 32 + h * 4);
#pragma unroll
    for (int j = 0; j < 8; ++j)
        wst[j] = *reinterpret_cast<const short8*>(wsrc + 16384 + (j * 256 + tid) * 8);
    __syncthreads();

    for (int c = 0; c < 12; ++c) {
        const int cb = c & 1;
        // convert A(c) -> bf16 hi/lo fragments (frees aA)
        short8 ah[2], al[2];
#pragma unroll
        for (int kcl = 0; kcl < 2; ++kcl) {
            const f32x4 x0 = aA[kcl * 2], x1 = aA[kcl * 2 + 1];
#pragma unroll
            for (int j = 0; j < 8; ++j) {
                const float av = (j < 4) ? x0[j] : x1[j - 4];
                const unsigned short h = f2bf(av);
                ah[kcl][j] = (short)h;
                al[kcl][j] = (short)f2bf(av - bf2f(h));
            }
        }
        // issue A(c+1) into freed regs
        if (c < 11) {
#pragma unroll
            for (int kcl = 0; kcl < 2; ++kcl)
#pragma unroll
                for (int h = 0; h < 2; ++h)
                    aA[kcl * 2 + h] = *reinterpret_cast<const f32x4*>(
                        ap + (c + 1) * 64 + kcl * 32 + h * 4);
        }
        // compute chunk c from lds[cb]
#pragma unroll
        for (int kcl = 0; kcl < 2; ++kcl) {
            short8 wf[8];
#pragma unroll
            for (int n = 0; n < 8; ++n)
                wf[n] = *reinterpret_cast<const short8*>(
                    &lds[cb][kcl * 4096 + n * 512 + lane * 8]);
#pragma unroll
            for (int n = 0; n < 8; ++n)
                acc[n] = __builtin_amdgcn_mfma_f32_16x16x32_bf16(ah[kcl], wf[n], acc[n], 0, 0, 0);
#pragma unroll
            for (int n = 0; n < 8; ++n)
                acc[n] = __builtin_amdgcn_mfma_f32_16x16x32_bf16(al[kcl], wf[n], acc[n], 0, 0, 0);
#pragma unroll
            for (int n = 0; n < 8; ++n)
                wf[n] = *reinterpret_cast<const short8*>(
                    &lds[cb][8192 + kcl * 4096 + n * 512 + lane * 8]);
#pragma unroll
            for (int n = 0; n < 8; ++n)
                acc[n] = __builtin_amdgcn_mfma_f32_16x16x32_bf16(ah[kcl], wf[n], acc[n], 0, 0, 0);
        }
        // write staged W(c+1) into the other buffer; issue W(c+2)
        if (c < 11) {
#pragma unroll
            for (int j = 0; j < 8; ++j)
                *reinterpret_cast<short8*>(&lds[cb ^ 1][(j * 256 + tid) * 8]) = wst[j];
        }
        if (c < 10) {
#pragma unroll
            for (int j = 0; j < 8; ++j)
                wst[j] = *reinterpret_cast<const short8*>(
                    wsrc + (size_t)(c + 2) * 16384 + (j * 256 + tid) * 8);
        }
        __syncthreads();
    }

    // epilogue: bias, row L2 norm, mask-zero, bf16 store
#pragma unroll
    for (int n = 0; n < 8; ++n)
#pragma unroll
        for (int i2 = 0; i2 < 4; ++i2) acc[n][i2] += bb[n];
    float ss[4];
#pragma unroll
    for (int i2 = 0; i2 < 4; ++i2) {
        float s = 0.f;
#pragma unroll
        for (int n = 0; n < 8; ++n) s += acc[n][i2] * acc[n][i2];
        s += __shfl_xor(s, 1); s += __shfl_xor(s, 2);
        s += __shfl_xor(s, 4); s += __shfl_xor(s, 8);
        ss[i2] = s;
    }
#pragma unroll
    for (int i2 = 0; i2 < 4; ++i2) {
        const int rowl = w * 16 + lq * 4 + i2;
        float inv = 1.0f / fmaxf(sqrtf(ss[i2]), 1e-12f);
        if (mp[rowl] == 0) inv = 0.f;   // fold mask into embedding
#pragma unroll
        for (int n = 0; n < 8; ++n)
            emb[(size_t)(rowg + rowl) * 128 + n * 16 + lr] = f2bf(acc[n][i2] * inv);
    }
}

// ---------------- maxsim: barrier-free, wave = 4 labels x 256 text rows ----------------
__global__ __launch_bounds__(256, 2) void maxsim_kernel(
    const unsigned short* __restrict__ temb,  // [32768][128] bf16
    const unsigned short* __restrict__ lemb,  // [4096][128] bf16
    float* __restrict__ sums)                 // [128][128] raw col-max sums
{
    const int t = blockIdx.x;
    const int bg = blockIdx.y;
    const int tid = threadIdx.x;
    const int lane = tid & 63, w = tid >> 6;
    const int lq = lane >> 4, lr = lane & 15;
    const short* tp = reinterpret_cast<const short*>(temb);
    const short* lp = reinterpret_cast<const short*>(lemb);
    const int l0 = bg * 16 + w * 4;

    short8 bfr[8][4];
#pragma unroll
    for (int n = 0; n < 8; ++n)
#pragma unroll
        for (int kc = 0; kc < 4; ++kc)
            bfr[n][kc] = *reinterpret_cast<const short8*>(
                lp + (size_t)(l0 * 32 + n * 16 + lr) * 128 + kc * 32 + lq * 8);

    f32x4 cmx[8];
#pragma unroll
    for (int n = 0; n < 8; ++n) cmx[n] = (f32x4)(-1e30f);

    const short* ap0 = tp + (size_t)(t * 256 + lr) * 128 + lq * 8;

    for (int m = 0; m < 16; ++m) {
        short8 afr[4];
#pragma unroll
        for (int kc = 0; kc < 4; ++kc)
            afr[kc] = *reinterpret_cast<const short8*>(ap0 + (size_t)m * 16 * 128 + kc * 32);
        f32x4 acc[8];
#pragma unroll
        for (int n = 0; n < 8; ++n) acc[n] = (f32x4)(0.f);
#pragma unroll
        for (int kc = 0; kc < 4; ++kc)
#pragma unroll
            for (int n = 0; n < 8; ++n)
                acc[n] = __builtin_amdgcn_mfma_f32_16x16x32_bf16(afr[kc], bfr[n][kc], acc[n], 0, 0, 0);
#pragma unroll
        for (int n = 0; n < 8; ++n) {
            cmx[n][0] = fmaxf(cmx[n][0], acc[n][0]);
            cmx[n][1] = fmaxf(cmx[n][1], acc[n][1]);
            cmx[n][2] = fmaxf(cmx[n][2], acc[n][2]);
            cmx[n][3] = fmaxf(cmx[n][3], acc[n][3]);
        }
    }

    float s[8];
#pragma unroll
    for (int n = 0; n < 8; ++n) {
        float v = fmaxf(fmaxf(cmx[n][0], cmx[n][1]), fmaxf(cmx[n][2], cmx[n][3]));
        v = fmaxf(v, __shfl_xor(v, 16));
        v = fmaxf(v, __shfl_xor(v, 32));
        v += __shfl_xor(v, 1);
        v += __shfl_xor(v, 2);
        v += __shfl_xor(v, 4);
        v += __shfl_xor(v, 8);
        s[n] = v;
    }
    if (lane == 0) {
#pragma unroll
        for (int li = 0; li < 4; ++li)
            sums[t * 128 + l0 + li] = s[2 * li] + s[2 * li + 1];
    }
}

// ---------------- finalize stage 1: 64 blocks, sigmoid + partial BCE ----------------
__global__ __launch_bounds__(256) void finalize_part(
    const float* __restrict__ sums, const int* __restrict__ lmask,
    const float* __restrict__ targets, const float* __restrict__ scale_p,
    float* __restrict__ out, float* __restrict__ partials)
{
    __shared__ float cl[128];
    const int tid = threadIdx.x;
    if (tid < 128) {
        int c = 0;
#pragma unroll
        for (int r = 0; r < 32; ++r) c += lmask[tid * 32 + r];
        cl[tid] = fmaxf((float)c, 1.0f);
    }
    __syncthreads();
    const float scale = *scale_p;
    const int i = blockIdx.x * 256 + tid;
    const float x = scale * sums[i] / cl[i & 127];
    const float tg = targets[i];
    out[1 + i] = 1.0f / (1.0f + expf(-x));
    float sum = fmaxf(x, 0.f) - x * tg + log1pf(expf(-fabsf(x)));
#pragma unroll
    for (int msk = 32; msk >= 1; msk >>= 1) sum += __shfl_xor(sum, msk);
    __shared__ float part[4];
    if ((tid & 63) == 0) part[tid >> 6] = sum;
    __syncthreads();
    if (tid == 0)
        partials[blockIdx.x] = part[0] + part[1] + part[2] + part[3];
}

// ---------------- finalize stage 2: 1 wave reduces 64 partials ----------------
__global__ void finalize_sum(const float* __restrict__ partials, float* __restrict__ out)
{
    float v = partials[threadIdx.x];
#pragma unroll
    for (int msk = 32; msk >= 1; msk >>= 1) v += __shfl_xor(v, msk);
    if (threadIdx.x == 0) out[0] = v * (1.0f / 16384.0f);
}

extern "C" void kernel_launch(void* const* d_in, const int* in_sizes, int n_in,
                              void* d_out, int out_size, void* d_ws, size_t ws_size,
                              hipStream_t stream) {
    const float* text_hidden  = (const float*)d_in[0];
    const float* label_hidden = (const float*)d_in[1];
    const int*   text_mask    = (const int*)d_in[2];
    const int*   label_mask   = (const int*)d_in[3];
    const float* targets      = (const float*)d_in[4];
    const float* W_proj       = (const float*)d_in[5];
    const float* b_proj       = (const float*)d_in[6];
    const float* score_scale  = (const float*)d_in[7];
    float* out = (float*)d_out;

    char* ws = (char*)d_ws;
    unsigned short* emb      = (unsigned short*)(ws);            // 36864*128*2 = 9437184 B
    float*          sums     = (float*)(ws + 9437184);           // 64 KB
    unsigned short* wfrag    = (unsigned short*)(ws + 9502720);  // 384 KB
    float*          partials = (float*)(ws + 9895936);           // 256 B

    prep_w_kernel<<<48, 256, 0, stream>>>(W_proj, wfrag);
    proj_mfma_kernel<<<576, 256, 0, stream>>>(text_hidden, label_hidden, wfrag,
                                              b_proj, text_mask, label_mask, emb);
    maxsim_kernel<<<dim3(128, 8), 256, 0, stream>>>(emb, emb + (size_t)32768 * 128, sums);
    finalize_part<<<64, 256, 0, stream>>>(sums, label_mask, targets, score_scale,
                                          out, partials);
    finalize_sum<<<1, 64, 0, stream>>>(partials, out);
}